// Round 6
// baseline (89.005 us; speedup 1.0000x reference)
//
#include <hip/hip_runtime.h>

// dist[pix, o] = ||x[pix]||^2 + ||omega[o]||^2 - 2 * x.omega
// M = 262144 pixels, O = 256 protos, D = 64.
// Round-6: EXACT round-5 structure. Single change: x loads are PLAIN instead
// of nontemporal. Theory: nt loads no-allocate in L1/L2, so the half-granule
// load pattern (16B requested per 32B span; complementary halves in the next
// load instr) re-fetches every 64B granule twice from HBM. Plain loads let L1
// serve the second half from the first fetch -> read traffic halves.

typedef __attribute__((ext_vector_type(4))) float f32x4;
typedef __attribute__((ext_vector_type(8))) short s16x8;
typedef __attribute__((ext_vector_type(4))) unsigned int u32x4;

constexpr int D_ = 64;
constexpr int O_ = 256;
constexpr int M_ = 16 * 128 * 128;           // 262144
constexpr int ITERS = 4;
constexpr int PIX_PER_BLOCK = 4 * 16 * ITERS; // 256
constexpr int NBLOCKS = M_ / PIX_PER_BLOCK;   // 1024

__device__ __forceinline__ unsigned short f2bf(float f) {
    // round-to-nearest-even fp32 -> bf16
    unsigned u = __builtin_bit_cast(unsigned, f);
    u += 0x7FFFu + ((u >> 16) & 1u);
    return (unsigned short)(u >> 16);
}

__global__ __launch_bounds__(256, 4) void dist_kernel(
    const float* __restrict__ x,
    const float* __restrict__ om,
    float* __restrict__ out)
{
    // [ (t*2+s)*64 + lane ] : per-lane 16B bf16 A-fragment of proto-tile t, k-step s
    __shared__ u32x4 lfrag[32 * 64];          // 32 KiB
    __shared__ __align__(16) float lp2[O_];   // 1 KiB

    const int tid  = threadIdx.x;
    const int wave = tid >> 6;
    const int lane = tid & 63;
    const int lr   = lane & 15;   // A-frag: proto-in-tile ; B-frag/out: pixel-in-tile
    const int lg   = lane >> 4;   // k-group

    // ---------- once per block: omega -> bf16 fragments + p2, into LDS ------
#pragma unroll
    for (int tt = 0; tt < 4; ++tt) {
        const int t = wave * 4 + tt;
        const float* src = om + (t * 16 + lr) * D_ + lg * 8;
        f32x4 v0 = *(const f32x4*)(src);
        f32x4 v1 = *(const f32x4*)(src + 4);
        f32x4 v2 = *(const f32x4*)(src + 32);
        f32x4 v3 = *(const f32x4*)(src + 36);
        float p2p = 0.f;
        s16x8 f0, f1;
#pragma unroll
        for (int j = 0; j < 4; ++j) {
            f0[j]     = (short)f2bf(v0[j]); p2p += v0[j] * v0[j];
            f0[4 + j] = (short)f2bf(v1[j]); p2p += v1[j] * v1[j];
            f1[j]     = (short)f2bf(v2[j]); p2p += v2[j] * v2[j];
            f1[4 + j] = (short)f2bf(v3[j]); p2p += v3[j] * v3[j];
        }
        lfrag[(t * 2 + 0) * 64 + lane] = __builtin_bit_cast(u32x4, f0);
        lfrag[(t * 2 + 1) * 64 + lane] = __builtin_bit_cast(u32x4, f1);
        p2p += __shfl_xor(p2p, 16);
        p2p += __shfl_xor(p2p, 32);
        if (lg == 0) lp2[t * 16 + lr] = p2p;   // lanes 0..15, conflict-free
    }
    __syncthreads();

    // ---------- steady state: 16 pixels per wave per iteration --------------
    const int pix0 = blockIdx.x * PIX_PER_BLOCK;
    for (int it = 0; it < ITERS; ++it) {
        const int rbase = pix0 + it * 64 + wave * 16;

        // B-frag (x): lane holds pixel (rbase+lr), k = lg*8.. (+s*32)
        // PLAIN loads — the one change vs round 5
        const float* xs = x + (rbase + lr) * D_ + lg * 8;
        f32x4 a0 = *(const f32x4*)(xs);
        f32x4 a1 = *(const f32x4*)(xs + 4);
        f32x4 a2 = *(const f32x4*)(xs + 32);
        f32x4 a3 = *(const f32x4*)(xs + 36);
        s16x8 Bx0, Bx1;
        float x2p = 0.f;
#pragma unroll
        for (int j = 0; j < 4; ++j) {
            Bx0[j]     = (short)f2bf(a0[j]); x2p += a0[j] * a0[j];
            Bx0[4 + j] = (short)f2bf(a1[j]); x2p += a1[j] * a1[j];
            Bx1[j]     = (short)f2bf(a2[j]); x2p += a2[j] * a2[j];
            Bx1[4 + j] = (short)f2bf(a3[j]); x2p += a3[j] * a3[j];
        }
        // full ||x||^2 of pixel (rbase+lr); col of C is lr so no re-shuffle
        x2p += __shfl_xor(x2p, 16);
        x2p += __shfl_xor(x2p, 32);

        float* obase = out + (size_t)(rbase + lr) * O_;

#pragma unroll 4
        for (int t = 0; t < 16; ++t) {
            s16x8 A0 = __builtin_bit_cast(s16x8, lfrag[(t * 2 + 0) * 64 + lane]);
            s16x8 A1 = __builtin_bit_cast(s16x8, lfrag[(t * 2 + 1) * 64 + lane]);
            f32x4 acc = {0.f, 0.f, 0.f, 0.f};
            acc = __builtin_amdgcn_mfma_f32_16x16x32_bf16(A0, Bx0, acc, 0, 0, 0);
            acc = __builtin_amdgcn_mfma_f32_16x16x32_bf16(A1, Bx1, acc, 0, 0, 0);
            // C layout: row(=proto) = lg*4 + j, col(=pixel) = lr
            const f32x4 b4 = *(const f32x4*)&lp2[t * 16 + lg * 4];  // broadcast
            f32x4 val;
#pragma unroll
            for (int j = 0; j < 4; ++j)
                val[j] = (x2p + b4[j]) - 2.f * acc[j];
            *(f32x4*)(obase + t * 16 + lg * 4) = val;   // plain store
        }
    }
}

extern "C" void kernel_launch(void* const* d_in, const int* in_sizes, int n_in,
                              void* d_out, int out_size, void* d_ws, size_t ws_size,
                              hipStream_t stream) {
    const float* x  = (const float*)d_in[0];   // [16,128,128,64] fp32
    const float* om = (const float*)d_in[1];   // [256,64] fp32
    float* out = (float*)d_out;                // [16,128,128,256,1] fp32

    dist_kernel<<<dim3(NBLOCKS), dim3(256), 0, stream>>>(x, om, out);
}

// Round 7
// 79.815 us; speedup vs baseline: 1.1152x; 1.1152x over previous
//
#include <hip/hip_runtime.h>

// dist[pix, o] = ||x[pix]||^2 + ||omega[o]||^2 - 2 * x.omega
// M = 262144 pixels, O = 256 protos, D = 64.
// Round-7: R5 config (nt loads, plain stores, LDS omega fragments, swapped
// MFMA) + FULL-GRANULE load pattern. MFMA's k-axis is permutation-invariant
// when the same data-k permutation is applied to BOTH operands. We pick the
// permutation that makes the contiguous load (instr i covers bytes
// [i*64 + lg*16) of each 256B pixel row) exactly the fragment layout:
// every 64B granule fetched exactly once per wave, even with no-allocate nt
// loads (old pattern half-touched each granule twice -> 2x read traffic).

typedef __attribute__((ext_vector_type(4))) float f32x4;
typedef __attribute__((ext_vector_type(8))) short s16x8;
typedef __attribute__((ext_vector_type(4))) unsigned int u32x4;

constexpr int D_ = 64;
constexpr int O_ = 256;
constexpr int M_ = 16 * 128 * 128;           // 262144
constexpr int ITERS = 4;
constexpr int PIX_PER_BLOCK = 4 * 16 * ITERS; // 256
constexpr int NBLOCKS = M_ / PIX_PER_BLOCK;   // 1024

__device__ __forceinline__ unsigned short f2bf(float f) {
    // round-to-nearest-even fp32 -> bf16
    unsigned u = __builtin_bit_cast(unsigned, f);
    u += 0x7FFFu + ((u >> 16) & 1u);
    return (unsigned short)(u >> 16);
}

__global__ __launch_bounds__(256, 4) void dist_kernel(
    const float* __restrict__ x,
    const float* __restrict__ om,
    float* __restrict__ out)
{
    // [ (t*2+s)*64 + lane ] : per-lane 16B bf16 A-fragment of proto-tile t, k-step s
    __shared__ u32x4 lfrag[32 * 64];          // 32 KiB
    __shared__ __align__(16) float lp2[O_];   // 1 KiB

    const int tid  = threadIdx.x;
    const int wave = tid >> 6;
    const int lane = tid & 63;
    const int lr   = lane & 15;   // A-frag: proto-in-tile ; B-frag/out: pixel-in-tile
    const int lg   = lane >> 4;   // k-group

    // data-k permutation: hardware (step s, group lg, j) <-> data float
    //   j<4 : s*32 + lg*4 + j          (chunk 16*(2s)   + 4lg)
    //   j>=4: s*32 + 16 + lg*4 + (j-4) (chunk 16*(2s+1) + 4lg)
    // applied identically to omega (A) and x (B) fragments.

    // ---------- once per block: omega -> bf16 fragments + p2, into LDS ------
#pragma unroll
    for (int tt = 0; tt < 4; ++tt) {
        const int t = wave * 4 + tt;
        const float* src = om + (t * 16 + lr) * D_ + lg * 4;
        f32x4 v0 = *(const f32x4*)(src);        // floats  4lg..      (s0 lo)
        f32x4 v1 = *(const f32x4*)(src + 16);   // floats 16+4lg..    (s0 hi)
        f32x4 v2 = *(const f32x4*)(src + 32);   // floats 32+4lg..    (s1 lo)
        f32x4 v3 = *(const f32x4*)(src + 48);   // floats 48+4lg..    (s1 hi)
        float p2p = 0.f;
        s16x8 f0, f1;
#pragma unroll
        for (int j = 0; j < 4; ++j) {
            f0[j]     = (short)f2bf(v0[j]); p2p += v0[j] * v0[j];
            f0[4 + j] = (short)f2bf(v1[j]); p2p += v1[j] * v1[j];
            f1[j]     = (short)f2bf(v2[j]); p2p += v2[j] * v2[j];
            f1[4 + j] = (short)f2bf(v3[j]); p2p += v3[j] * v3[j];
        }
        lfrag[(t * 2 + 0) * 64 + lane] = __builtin_bit_cast(u32x4, f0);
        lfrag[(t * 2 + 1) * 64 + lane] = __builtin_bit_cast(u32x4, f1);
        p2p += __shfl_xor(p2p, 16);
        p2p += __shfl_xor(p2p, 32);
        if (lg == 0) lp2[t * 16 + lr] = p2p;   // lanes 0..15, conflict-free
    }
    __syncthreads();

    // ---------- steady state: 16 pixels per wave per iteration --------------
    const int pix0 = blockIdx.x * PIX_PER_BLOCK;
    for (int it = 0; it < ITERS; ++it) {
        const int rbase = pix0 + it * 64 + wave * 16;

        // B-frag (x): lane holds pixel (rbase+lr); each load instr covers
        // whole 64B granules (4 lg lanes contiguous within each row chunk).
        const float* xs = x + (rbase + lr) * D_ + lg * 4;
        f32x4 a0 = __builtin_nontemporal_load((const f32x4*)(xs));
        f32x4 a1 = __builtin_nontemporal_load((const f32x4*)(xs + 16));
        f32x4 a2 = __builtin_nontemporal_load((const f32x4*)(xs + 32));
        f32x4 a3 = __builtin_nontemporal_load((const f32x4*)(xs + 48));
        s16x8 Bx0, Bx1;
        float x2p = 0.f;
#pragma unroll
        for (int j = 0; j < 4; ++j) {
            Bx0[j]     = (short)f2bf(a0[j]); x2p += a0[j] * a0[j];
            Bx0[4 + j] = (short)f2bf(a1[j]); x2p += a1[j] * a1[j];
            Bx1[j]     = (short)f2bf(a2[j]); x2p += a2[j] * a2[j];
            Bx1[4 + j] = (short)f2bf(a3[j]); x2p += a3[j] * a3[j];
        }
        // full ||x||^2 of pixel (rbase+lr); col of C is lr so no re-shuffle
        x2p += __shfl_xor(x2p, 16);
        x2p += __shfl_xor(x2p, 32);

        float* obase = out + (size_t)(rbase + lr) * O_;

#pragma unroll 4
        for (int t = 0; t < 16; ++t) {
            s16x8 A0 = __builtin_bit_cast(s16x8, lfrag[(t * 2 + 0) * 64 + lane]);
            s16x8 A1 = __builtin_bit_cast(s16x8, lfrag[(t * 2 + 1) * 64 + lane]);
            f32x4 acc = {0.f, 0.f, 0.f, 0.f};
            acc = __builtin_amdgcn_mfma_f32_16x16x32_bf16(A0, Bx0, acc, 0, 0, 0);
            acc = __builtin_amdgcn_mfma_f32_16x16x32_bf16(A1, Bx1, acc, 0, 0, 0);
            // C layout: row(=proto) = lg*4 + j, col(=pixel) = lr
            const f32x4 b4 = *(const f32x4*)&lp2[t * 16 + lg * 4];  // broadcast
            f32x4 val;
#pragma unroll
            for (int j = 0; j < 4; ++j)
                val[j] = (x2p + b4[j]) - 2.f * acc[j];
            *(f32x4*)(obase + t * 16 + lg * 4) = val;   // plain store
        }
    }
}

extern "C" void kernel_launch(void* const* d_in, const int* in_sizes, int n_in,
                              void* d_out, int out_size, void* d_ws, size_t ws_size,
                              hipStream_t stream) {
    const float* x  = (const float*)d_in[0];   // [16,128,128,64] fp32
    const float* om = (const float*)d_in[1];   // [256,64] fp32
    float* out = (float*)d_out;                // [16,128,128,256,1] fp32

    dist_kernel<<<dim3(NBLOCKS), dim3(256), 0, stream>>>(x, om, out);
}